// Round 1
// baseline (290.442 us; speedup 1.0000x reference)
//
#include <hip/hip_runtime.h>
#include <hip/hip_bf16.h>
#include <stdint.h>

#define B_ 8192
#define IN_ 1024
#define H_ 1024
#define OUT_ 512
#define KC 2048   // IN_+H_
#define N4 4096   // 4*H_

typedef __bf16 bf16_t;
typedef __bf16 bf16x8 __attribute__((ext_vector_type(8)));
typedef float f32x4 __attribute__((ext_vector_type(4)));

__device__ __forceinline__ void gload_lds16(const void* g, void* l) {
  __builtin_amdgcn_global_load_lds(
      (const __attribute__((address_space(1))) uint32_t*)g,
      (__attribute__((address_space(3))) uint32_t*)l, 16, 0, 0);
}

__device__ __forceinline__ float fsigmoid(float x) {
  return __builtin_amdgcn_rcpf(1.0f + __expf(-x));
}
__device__ __forceinline__ float ftanh(float x) {
  return 2.0f * __builtin_amdgcn_rcpf(1.0f + __expf(-2.0f * x)) - 1.0f;
}

// ---------------- pack kernels ----------------

// combined[row][0:1024] = x[row], combined[row][1024:2048] = h[row], bf16
__global__ __launch_bounds__(256) void pack_combined(
    const float* __restrict__ x, const float* __restrict__ h,
    bf16_t* __restrict__ out) {
  const int row = blockIdx.x;
  const int j = threadIdx.x * 8;
  const float* src = (j < IN_) ? (x + (size_t)row * IN_ + j)
                               : (h + (size_t)row * H_ + (j - IN_));
  float4 a = ((const float4*)src)[0];
  float4 b = ((const float4*)src)[1];
  bf16x8 v;
  v[0] = (bf16_t)a.x; v[1] = (bf16_t)a.y; v[2] = (bf16_t)a.z; v[3] = (bf16_t)a.w;
  v[4] = (bf16_t)b.x; v[5] = (bf16_t)b.y; v[6] = (bf16_t)b.z; v[7] = (bf16_t)b.w;
  *(bf16x8*)(out + (size_t)row * KC + j) = v;
}

// dst[n][k] = src[k][n] as bf16. src is [K][N] f32, dst row stride = K.
// grid: (N/64, K/64), block 256.
__global__ __launch_bounds__(256) void transpose_pack(
    const float* __restrict__ src, bf16_t* __restrict__ dst, int K, int N) {
  __shared__ float tile[64][65];
  const int k0 = blockIdx.y * 64, n0 = blockIdx.x * 64;
  const int t = threadIdx.x;
  const int tr = t >> 4, tc4 = (t & 15) * 4;
#pragma unroll
  for (int r = 0; r < 4; ++r) {
    const int k = tr + r * 16;
    float4 v = *(const float4*)(src + (size_t)(k0 + k) * N + n0 + tc4);
    tile[k][tc4] = v.x; tile[k][tc4 + 1] = v.y;
    tile[k][tc4 + 2] = v.z; tile[k][tc4 + 3] = v.w;
  }
  __syncthreads();
  const int nr = t >> 3, kc8 = (t & 7) * 8;
#pragma unroll
  for (int r = 0; r < 2; ++r) {
    const int n = nr + r * 32;
    bf16x8 v;
#pragma unroll
    for (int q = 0; q < 8; ++q) v[q] = (bf16_t)tile[kc8 + q][n];
    *(bf16x8*)(dst + (size_t)(n0 + n) * K + k0 + kc8) = v;
  }
}

// ---------------- GEMM (m97 structure) ----------------
// C[M][N] = A[M][K] * Bt[N][K]^T ; 128x128 tile, BK=64, 4 waves (2x2 of 64x64)
// EPI 0: store bf16, no bias. EPI 1: store f32 + bias.
template <int EPI>
__global__ __launch_bounds__(256) void gemm_bt(
    const bf16_t* __restrict__ A, const bf16_t* __restrict__ Bt,
    void* __restrict__ Cout, const float* __restrict__ bias,
    int M, int N, int K) {
  __shared__ bf16_t As[128 * 64];
  __shared__ bf16_t Bs[128 * 64];
  const int tid = threadIdx.x;
  const int lane = tid & 63;
  const int wave = tid >> 6;
  const int m0 = blockIdx.y * 128;
  const int n0 = blockIdx.x * 128;
  const int wr = wave >> 1, wc = wave & 1;
  const int l15 = lane & 15, l4 = lane >> 4;

  f32x4 acc[4][4] = {};

  const int srow = tid >> 3;       // 0..31 : tile row within issue
  const int skel = (tid & 7) * 8;  // k element 0..56
  const size_t aBase = (size_t)(m0 + srow) * K + skel;
  const size_t bBase = (size_t)(n0 + srow) * K + skel;
  char* aL = (char*)As + wave * 1024;
  char* bL = (char*)Bs + wave * 1024;

  for (int kt = 0; kt < K; kt += 64) {
    __syncthreads();  // previous tile's compute done
#pragma unroll
    for (int i = 0; i < 4; ++i) {
      gload_lds16(A + aBase + (size_t)i * 32 * K + kt, aL + i * 4096);
      gload_lds16(Bt + bBase + (size_t)i * 32 * K + kt, bL + i * 4096);
    }
    __syncthreads();  // drains vmcnt(0): staged data visible
#pragma unroll
    for (int kk = 0; kk < 2; ++kk) {
      bf16x8 af[4], bq[4];
#pragma unroll
      for (int mi = 0; mi < 4; ++mi)
        af[mi] = *(const bf16x8*)((const char*)As +
                 (wr * 64 + mi * 16 + l15) * 128 + kk * 64 + l4 * 16);
#pragma unroll
      for (int ni = 0; ni < 4; ++ni)
        bq[ni] = *(const bf16x8*)((const char*)Bs +
                 (wc * 64 + ni * 16 + l15) * 128 + kk * 64 + l4 * 16);
#pragma unroll
      for (int mi = 0; mi < 4; ++mi)
#pragma unroll
        for (int ni = 0; ni < 4; ++ni)
          acc[mi][ni] = __builtin_amdgcn_mfma_f32_16x16x32_bf16(
              af[mi], bq[ni], acc[mi][ni], 0, 0, 0);
    }
  }

  // C/D layout (verified m89/m91): col = lane&15, row = (lane>>4)*4 + reg
  const int col = n0 + wc * 64 + l15;
  const int row0 = m0 + wr * 64 + l4 * 4;
  if (EPI == 0) {
    bf16_t* C = (bf16_t*)Cout;
#pragma unroll
    for (int mi = 0; mi < 4; ++mi)
#pragma unroll
      for (int ni = 0; ni < 4; ++ni)
#pragma unroll
        for (int q = 0; q < 4; ++q)
          C[(size_t)(row0 + mi * 16 + q) * N + col + ni * 16] =
              (bf16_t)acc[mi][ni][q];
  } else {
    float* C = (float*)Cout;
#pragma unroll
    for (int ni = 0; ni < 4; ++ni) {
      const float bv = bias[col + ni * 16];
#pragma unroll
      for (int mi = 0; mi < 4; ++mi)
#pragma unroll
        for (int q = 0; q < 4; ++q)
          C[(size_t)(row0 + mi * 16 + q) * N + col + ni * 16] =
              acc[mi][ni][q] + bv;
    }
  }
}

// ---------------- LSTM elementwise ----------------
__global__ __launch_bounds__(256) void lstm_eltwise(
    const bf16_t* __restrict__ gates, const float* __restrict__ c,
    const float* __restrict__ bi, const float* __restrict__ bfg,
    const float* __restrict__ bo, const float* __restrict__ bc,
    float* __restrict__ h_out, float* __restrict__ c_out,
    bf16_t* __restrict__ hb) {
  const int idx = blockIdx.x * 256 + threadIdx.x;
  const int row = idx >> 7;        // H_/8 = 128 threads per row
  const int j = (idx & 127) * 8;
  const size_t gbase = (size_t)row * N4 + j;
  bf16x8 gi = *(const bf16x8*)(gates + gbase);
  bf16x8 gf = *(const bf16x8*)(gates + gbase + H_);
  bf16x8 go = *(const bf16x8*)(gates + gbase + 2 * H_);
  bf16x8 gc = *(const bf16x8*)(gates + gbase + 3 * H_);
  const size_t cbase = (size_t)row * H_ + j;
  float4 c0 = *(const float4*)(c + cbase);
  float4 c1 = *(const float4*)(c + cbase + 4);
  float cv[8] = {c0.x, c0.y, c0.z, c0.w, c1.x, c1.y, c1.z, c1.w};
  float hnew[8], cnew[8];
  bf16x8 hbv;
#pragma unroll
  for (int q = 0; q < 8; ++q) {
    float I = fsigmoid((float)gi[q] + bi[j + q]);
    float F = fsigmoid((float)gf[q] + bfg[j + q]);
    float O = fsigmoid((float)go[q] + bo[j + q]);
    float Ct = ftanh((float)gc[q] + bc[j + q]);
    float cn = F * cv[q] + I * Ct;
    cnew[q] = cn;
    float hn = O * ftanh(cn);
    hnew[q] = hn;
    hbv[q] = (bf16_t)hn;
  }
  *(float4*)(c_out + cbase) = make_float4(cnew[0], cnew[1], cnew[2], cnew[3]);
  *(float4*)(c_out + cbase + 4) = make_float4(cnew[4], cnew[5], cnew[6], cnew[7]);
  *(float4*)(h_out + cbase) = make_float4(hnew[0], hnew[1], hnew[2], hnew[3]);
  *(float4*)(h_out + cbase + 4) = make_float4(hnew[4], hnew[5], hnew[6], hnew[7]);
  *(bf16x8*)(hb + cbase) = hbv;
}

// ---------------- launcher ----------------
extern "C" void kernel_launch(void* const* d_in, const int* in_sizes, int n_in,
                              void* d_out, int out_size, void* d_ws,
                              size_t ws_size, hipStream_t stream) {
  const float* x = (const float*)d_in[0];
  const float* h = (const float*)d_in[1];
  const float* c = (const float*)d_in[2];
  const float* Wi = (const float*)d_in[3];
  const float* bi = (const float*)d_in[4];
  const float* Wf = (const float*)d_in[5];
  const float* bfg = (const float*)d_in[6];
  const float* Wo = (const float*)d_in[7];
  const float* bo = (const float*)d_in[8];
  const float* Wc = (const float*)d_in[9];
  const float* bc = (const float*)d_in[10];
  const float* Wy = (const float*)d_in[11];
  const float* by = (const float*)d_in[12];

  char* ws = (char*)d_ws;
  bf16_t* combined = (bf16_t*)ws;                                  // 33.5 MB
  bf16_t* Wt = (bf16_t*)(ws + 33554432);                           // 16.8 MB
  bf16_t* Wyt = (bf16_t*)(ws + 33554432 + 16777216);               // 1 MB
  bf16_t* gates = (bf16_t*)(ws + 33554432 + 16777216 + 1048576);   // 67 MB
  bf16_t* hb = (bf16_t*)(ws + 33554432 + 16777216 + 1048576 + 67108864);  // 16.8 MB

  float* y_out = (float*)d_out;
  float* h_out = y_out + (size_t)B_ * OUT_;
  float* c_out = h_out + (size_t)B_ * H_;

  // pack inputs to bf16
  pack_combined<<<dim3(B_), dim3(256), 0, stream>>>(x, h, combined);
  const float* Wg[4] = {Wi, Wf, Wo, Wc};
  for (int g = 0; g < 4; ++g)
    transpose_pack<<<dim3(H_ / 64, KC / 64), dim3(256), 0, stream>>>(
        Wg[g], Wt + (size_t)g * H_ * KC, KC, H_);
  transpose_pack<<<dim3(OUT_ / 64, H_ / 64), dim3(256), 0, stream>>>(
      Wy, Wyt, H_, OUT_);

  // gates = combined @ W_all   (bias added in eltwise)
  gemm_bt<0><<<dim3(N4 / 128, B_ / 128), dim3(256), 0, stream>>>(
      combined, Wt, (void*)gates, nullptr, B_, N4, KC);

  // elementwise LSTM cell
  lstm_eltwise<<<dim3(B_ * H_ / 8 / 256), dim3(256), 0, stream>>>(
      gates, c, bi, bfg, bo, bc, h_out, c_out, hb);

  // y = h_new @ Wy + by
  gemm_bt<1><<<dim3(OUT_ / 128, B_ / 128), dim3(256), 0, stream>>>(
      hb, Wyt, (void*)y_out, by, B_, OUT_, H_);
}

// Round 2
// 226.824 us; speedup vs baseline: 1.2805x; 1.2805x over previous
//
#include <hip/hip_runtime.h>
#include <hip/hip_bf16.h>
#include <stdint.h>

#define B_ 8192
#define IN_ 1024
#define H_ 1024
#define OUT_ 512
#define KC 2048   // IN_+H_
#define N4 4096   // 4*H_

typedef __bf16 bf16_t;
typedef __bf16 bf16x8 __attribute__((ext_vector_type(8)));
typedef float f32x4 __attribute__((ext_vector_type(4)));

__device__ __forceinline__ void gload_lds16(const void* g, void* l) {
  __builtin_amdgcn_global_load_lds(
      (const __attribute__((address_space(1))) uint32_t*)g,
      (__attribute__((address_space(3))) uint32_t*)l, 16, 0, 0);
}

__device__ __forceinline__ float fsigmoid(float x) {
  return __builtin_amdgcn_rcpf(1.0f + __expf(-x));
}
__device__ __forceinline__ float ftanh(float x) {
  return 2.0f * __builtin_amdgcn_rcpf(1.0f + __expf(-2.0f * x)) - 1.0f;
}

// ---------------- pack kernels ----------------

__global__ __launch_bounds__(256) void pack_combined(
    const float* __restrict__ x, const float* __restrict__ h,
    bf16_t* __restrict__ out) {
  const int row = blockIdx.x;
  const int j = threadIdx.x * 8;
  const float* src = (j < IN_) ? (x + (size_t)row * IN_ + j)
                               : (h + (size_t)row * H_ + (j - IN_));
  float4 a = ((const float4*)src)[0];
  float4 b = ((const float4*)src)[1];
  bf16x8 v;
  v[0] = (bf16_t)a.x; v[1] = (bf16_t)a.y; v[2] = (bf16_t)a.z; v[3] = (bf16_t)a.w;
  v[4] = (bf16_t)b.x; v[5] = (bf16_t)b.y; v[6] = (bf16_t)b.z; v[7] = (bf16_t)b.w;
  *(bf16x8*)(out + (size_t)row * KC + j) = v;
}

// dst[n][k] = src[k][n] as bf16. src is [K][N] f32, dst row stride = K.
__global__ __launch_bounds__(256) void transpose_pack(
    const float* __restrict__ src, bf16_t* __restrict__ dst, int K, int N) {
  __shared__ float tile[64][65];
  const int k0 = blockIdx.y * 64, n0 = blockIdx.x * 64;
  const int t = threadIdx.x;
  const int tr = t >> 4, tc4 = (t & 15) * 4;
#pragma unroll
  for (int r = 0; r < 4; ++r) {
    const int k = tr + r * 16;
    float4 v = *(const float4*)(src + (size_t)(k0 + k) * N + n0 + tc4);
    tile[k][tc4] = v.x; tile[k][tc4 + 1] = v.y;
    tile[k][tc4 + 2] = v.z; tile[k][tc4 + 3] = v.w;
  }
  __syncthreads();
  const int nr = t >> 3, kc8 = (t & 7) * 8;
#pragma unroll
  for (int r = 0; r < 2; ++r) {
    const int n = nr + r * 32;
    bf16x8 v;
#pragma unroll
    for (int q = 0; q < 8; ++q) v[q] = (bf16_t)tile[kc8 + q][n];
    *(bf16x8*)(dst + (size_t)(n0 + n) * K + k0 + kc8) = v;
  }
}

// ---------------- GEMM1: 256x256 8-phase template (m201 structure) ----------
// C[M][N] = A[M][K] * Bt[N][K]^T, bf16 out. M=8192 N=4096 K=2048.
// 8 waves (2Mx4N), per-wave 128x64. LDS 128KiB = 2buf x (A,B) x 2half x 16KB.
// Half-tile LDS layout: subtiled [8 rowgrp][2 kgrp][16r][32k] bf16, st_16x32
// swizzle: physical = logical ^ ((bit9)<<5). Stage side pre-swizzles the
// GLOBAL source per-lane (LDS dest stays linear, G21); read side applies the
// same XOR.
__global__ __launch_bounds__(512) void gemm1_8ph(
    const bf16_t* __restrict__ A, const bf16_t* __restrict__ Bt,
    bf16_t* __restrict__ C) {
  constexpr int K = KC, N = N4;
  constexpr int NT = K / 64;  // 32 K-tiles
  __shared__ char lds[131072];

  const int tid = threadIdx.x;
  const int lane = tid & 63;
  const int w = tid >> 6;
  const int wr = w >> 2, wc = w & 3;
  const int l15 = lane & 15, l4 = lane >> 4;

  // XCD-bijective swizzle: 512 blocks, 8 XCDs, 64 blocks/XCD.
  // by-fastest chunks: each XCD covers 2 bx (two 256-col B panels, 2MB -> L2).
  const int wg = blockIdx.x;
  const int swz = (wg & 7) * 64 + (wg >> 3);
  const int bx = swz >> 5;   // 0..15
  const int by = swz & 31;   // 0..31
  const int m0 = by * 256, n0 = bx * 256;

  // ---- staging: per-lane pre-swizzled global source ----
  const int jrow = lane >> 2;                                  // 0..15
  const int jcol = ((lane & 3) * 16) ^ ((lane >> 5) << 5);     // swizzled k-byte
  const char* Asrc = (const char*)A + (size_t)(m0 + w * 16 + jrow) * (K * 2) + jcol;
  const char* Bsrc = (const char*)Bt + (size_t)(n0 + w * 16 + jrow) * (K * 2) + jcol;
  char* ldsA = lds;            // + buf*65536 + h*16384 + chunk
  char* ldsB = lds + 32768;
  const int wchunk = w * 2048; // (w*2)*1024

#define STG_A(buf, h, tt) do {                                            \
    gload_lds16(Asrc + (size_t)(h) * 128 * (K * 2) + (size_t)(tt) * 128,  \
                ldsA + (buf) * 65536 + (h) * 16384 + wchunk);             \
    gload_lds16(Asrc + (size_t)(h) * 128 * (K * 2) + (size_t)(tt) * 128 + 64, \
                ldsA + (buf) * 65536 + (h) * 16384 + wchunk + 1024);      \
  } while (0)
#define STG_B(buf, h, tt) do {                                            \
    gload_lds16(Bsrc + (size_t)(h) * 128 * (K * 2) + (size_t)(tt) * 128,  \
                ldsB + (buf) * 65536 + (h) * 16384 + wchunk);             \
    gload_lds16(Bsrc + (size_t)(h) * 128 * (K * 2) + (size_t)(tt) * 128 + 64, \
                ldsB + (buf) * 65536 + (h) * 16384 + wchunk + 1024);      \
  } while (0)

  // ---- LDS read bases (swizzled) ----
  const int rdoff = l15 * 64 + ((l4 * 16) ^ ((l15 >> 3) << 5));
  const char* ldsArd = lds + wr * 16384 + rdoff;  // + buf*65536 + (mi*2+kk)*1024
  const char* ldsBrd = lds + 32768 + (wc >> 1) * 16384 + (wc & 1) * 8192 + rdoff;

  f32x4 acc[8][4] = {};
  bf16x8 fa[4][2], fb[4][2];

#define MFMA_Q(MIBASE, NIBASE)                                                \
  do {                                                                        \
    __builtin_amdgcn_s_setprio(1);                                            \
    _Pragma("unroll") for (int mi = 0; mi < 4; ++mi)                          \
        _Pragma("unroll") for (int ni = 0; ni < 2; ++ni)                      \
            _Pragma("unroll") for (int kk = 0; kk < 2; ++kk)                  \
                acc[(MIBASE) + mi][(NIBASE) + ni] =                           \
                    __builtin_amdgcn_mfma_f32_16x16x32_bf16(                  \
                        fa[mi][kk], fb[(NIBASE) + ni][kk],                    \
                        acc[(MIBASE) + mi][(NIBASE) + ni], 0, 0, 0);          \
    __builtin_amdgcn_s_setprio(0);                                            \
  } while (0)

  // ---- prologue: tile0 complete + tile1 {B0,A0,A1} in flight ----
  STG_B(0, 0, 0); STG_A(0, 0, 0); STG_A(0, 1, 0); STG_B(0, 1, 0);
  STG_B(1, 0, 1); STG_A(1, 0, 1); STG_A(1, 1, 1);
  asm volatile("s_waitcnt vmcnt(6)" ::: "memory");  // tile0's 8 loads landed
  __builtin_amdgcn_s_barrier();

  for (int t = 0; t < NT; ++t) {
    const int buf = t & 1;
    const int nbuf = buf ^ 1;
    const char* ard = ldsArd + buf * 65536;
    const char* brd = ldsBrd + buf * 65536;
    const bool st1 = (t + 1 < NT);
    const bool st2 = (t + 2 < NT);

    // ---- phase 1: quadrant (m-lo, n-lo); 12 ds_reads ----
#pragma unroll
    for (int mi = 0; mi < 4; ++mi)
#pragma unroll
      for (int kk = 0; kk < 2; ++kk)
        fa[mi][kk] = *(const bf16x8*)(ard + mi * 2048 + kk * 1024);
#pragma unroll
    for (int ni = 0; ni < 2; ++ni)
#pragma unroll
      for (int kk = 0; kk < 2; ++kk)
        fb[ni][kk] = *(const bf16x8*)(brd + ni * 2048 + kk * 1024);
    if (st1) STG_B(nbuf, 1, t + 1);   // (t+1).B1 -> other buffer
    __builtin_amdgcn_s_barrier();
    MFMA_Q(0, 0);
    __builtin_amdgcn_s_barrier();

    // ---- phase 2: (m-lo, n-hi); 4 ds_reads ----
#pragma unroll
    for (int ni = 2; ni < 4; ++ni)
#pragma unroll
      for (int kk = 0; kk < 2; ++kk)
        fb[ni][kk] = *(const bf16x8*)(brd + ni * 2048 + kk * 1024);
    __builtin_amdgcn_s_barrier();
    MFMA_Q(0, 2);
    __builtin_amdgcn_s_barrier();

    // ---- phase 3: (m-hi, n-lo); 8 ds_reads ----
#pragma unroll
    for (int mi = 0; mi < 4; ++mi)
#pragma unroll
      for (int kk = 0; kk < 2; ++kk)
        fa[mi][kk] = *(const bf16x8*)(ard + (mi + 4) * 2048 + kk * 1024);
    if (st2) STG_B(buf, 0, t + 2);    // B0 region free after P2 barrier
    __builtin_amdgcn_s_barrier();
    MFMA_Q(4, 0);
    __builtin_amdgcn_s_barrier();

    // ---- phase 4: (m-hi, n-hi); 0 ds_reads ----
    if (st2) { STG_A(buf, 0, t + 2); STG_A(buf, 1, t + 2); }  // A free after P3
    __builtin_amdgcn_s_barrier();
    MFMA_Q(4, 2);
    if (st2) asm volatile("s_waitcnt vmcnt(6)" ::: "memory");
    else     asm volatile("s_waitcnt vmcnt(0)" ::: "memory");
    __builtin_amdgcn_s_barrier();     // tile t+1 fully resident past here
  }

  // ---- epilogue: C/D layout col=lane&15, row=(lane>>4)*4+q ----
  const int col0 = n0 + wc * 64 + l15;
  const int row0 = m0 + wr * 128 + l4 * 4;
#pragma unroll
  for (int mi = 0; mi < 8; ++mi)
#pragma unroll
    for (int ni = 0; ni < 4; ++ni)
#pragma unroll
      for (int q = 0; q < 4; ++q)
        C[(size_t)(row0 + mi * 16 + q) * N + col0 + ni * 16] =
            (bf16_t)acc[mi][ni][q];
#undef STG_A
#undef STG_B
#undef MFMA_Q
}

// ---------------- GEMM2 (m97 structure, f32 out + bias) ----------------
__global__ __launch_bounds__(256) void gemm_bt_f32(
    const bf16_t* __restrict__ A, const bf16_t* __restrict__ Bt,
    float* __restrict__ Cout, const float* __restrict__ bias,
    int M, int N, int K) {
  __shared__ bf16_t As[128 * 64];
  __shared__ bf16_t Bs[128 * 64];
  const int tid = threadIdx.x;
  const int lane = tid & 63;
  const int wave = tid >> 6;
  const int m0 = blockIdx.y * 128;
  const int n0 = blockIdx.x * 128;
  const int wr = wave >> 1, wc = wave & 1;
  const int l15 = lane & 15, l4 = lane >> 4;

  f32x4 acc[4][4] = {};

  const int srow = tid >> 3;
  const int skel = (tid & 7) * 8;
  const size_t aBase = (size_t)(m0 + srow) * K + skel;
  const size_t bBase = (size_t)(n0 + srow) * K + skel;
  char* aL = (char*)As + wave * 1024;
  char* bL = (char*)Bs + wave * 1024;

  for (int kt = 0; kt < K; kt += 64) {
    __syncthreads();
#pragma unroll
    for (int i = 0; i < 4; ++i) {
      gload_lds16(A + aBase + (size_t)i * 32 * K + kt, aL + i * 4096);
      gload_lds16(Bt + bBase + (size_t)i * 32 * K + kt, bL + i * 4096);
    }
    __syncthreads();
#pragma unroll
    for (int kk = 0; kk < 2; ++kk) {
      bf16x8 af[4], bq[4];
#pragma unroll
      for (int mi = 0; mi < 4; ++mi)
        af[mi] = *(const bf16x8*)((const char*)As +
                 (wr * 64 + mi * 16 + l15) * 128 + kk * 64 + l4 * 16);
#pragma unroll
      for (int ni = 0; ni < 4; ++ni)
        bq[ni] = *(const bf16x8*)((const char*)Bs +
                 (wc * 64 + ni * 16 + l15) * 128 + kk * 64 + l4 * 16);
#pragma unroll
      for (int mi = 0; mi < 4; ++mi)
#pragma unroll
        for (int ni = 0; ni < 4; ++ni)
          acc[mi][ni] = __builtin_amdgcn_mfma_f32_16x16x32_bf16(
              af[mi], bq[ni], acc[mi][ni], 0, 0, 0);
    }
  }

  const int col = n0 + wc * 64 + l15;
  const int row0 = m0 + wr * 64 + l4 * 4;
#pragma unroll
  for (int ni = 0; ni < 4; ++ni) {
    const float bv = bias[col + ni * 16];
#pragma unroll
    for (int mi = 0; mi < 4; ++mi)
#pragma unroll
      for (int q = 0; q < 4; ++q)
        Cout[(size_t)(row0 + mi * 16 + q) * N + col + ni * 16] =
            acc[mi][ni][q] + bv;
  }
}

// ---------------- LSTM elementwise ----------------
__global__ __launch_bounds__(256) void lstm_eltwise(
    const bf16_t* __restrict__ gates, const float* __restrict__ c,
    const float* __restrict__ bi, const float* __restrict__ bfg,
    const float* __restrict__ bo, const float* __restrict__ bc,
    float* __restrict__ h_out, float* __restrict__ c_out,
    bf16_t* __restrict__ hb) {
  const int idx = blockIdx.x * 256 + threadIdx.x;
  const int row = idx >> 7;
  const int j = (idx & 127) * 8;
  const size_t gbase = (size_t)row * N4 + j;
  bf16x8 gi = *(const bf16x8*)(gates + gbase);
  bf16x8 gf = *(const bf16x8*)(gates + gbase + H_);
  bf16x8 go = *(const bf16x8*)(gates + gbase + 2 * H_);
  bf16x8 gc = *(const bf16x8*)(gates + gbase + 3 * H_);
  const size_t cbase = (size_t)row * H_ + j;
  float4 c0 = *(const float4*)(c + cbase);
  float4 c1 = *(const float4*)(c + cbase + 4);
  float cv[8] = {c0.x, c0.y, c0.z, c0.w, c1.x, c1.y, c1.z, c1.w};
  float hnew[8], cnew[8];
  bf16x8 hbv;
#pragma unroll
  for (int q = 0; q < 8; ++q) {
    float I = fsigmoid((float)gi[q] + bi[j + q]);
    float F = fsigmoid((float)gf[q] + bfg[j + q]);
    float O = fsigmoid((float)go[q] + bo[j + q]);
    float Ct = ftanh((float)gc[q] + bc[j + q]);
    float cn = F * cv[q] + I * Ct;
    cnew[q] = cn;
    float hn = O * ftanh(cn);
    hnew[q] = hn;
    hbv[q] = (bf16_t)hn;
  }
  *(float4*)(c_out + cbase) = make_float4(cnew[0], cnew[1], cnew[2], cnew[3]);
  *(float4*)(c_out + cbase + 4) = make_float4(cnew[4], cnew[5], cnew[6], cnew[7]);
  *(float4*)(h_out + cbase) = make_float4(hnew[0], hnew[1], hnew[2], hnew[3]);
  *(float4*)(h_out + cbase + 4) = make_float4(hnew[4], hnew[5], hnew[6], hnew[7]);
  *(bf16x8*)(hb + cbase) = hbv;
}

// ---------------- launcher ----------------
extern "C" void kernel_launch(void* const* d_in, const int* in_sizes, int n_in,
                              void* d_out, int out_size, void* d_ws,
                              size_t ws_size, hipStream_t stream) {
  const float* x = (const float*)d_in[0];
  const float* h = (const float*)d_in[1];
  const float* c = (const float*)d_in[2];
  const float* Wi = (const float*)d_in[3];
  const float* bi = (const float*)d_in[4];
  const float* Wf = (const float*)d_in[5];
  const float* bfg = (const float*)d_in[6];
  const float* Wo = (const float*)d_in[7];
  const float* bo = (const float*)d_in[8];
  const float* Wc = (const float*)d_in[9];
  const float* bc = (const float*)d_in[10];
  const float* Wy = (const float*)d_in[11];
  const float* by = (const float*)d_in[12];

  char* ws = (char*)d_ws;
  bf16_t* combined = (bf16_t*)ws;                                  // 33.5 MB
  bf16_t* Wt = (bf16_t*)(ws + 33554432);                           // 16.8 MB
  bf16_t* Wyt = (bf16_t*)(ws + 33554432 + 16777216);               // 1 MB
  bf16_t* gates = (bf16_t*)(ws + 33554432 + 16777216 + 1048576);   // 67 MB
  bf16_t* hb = (bf16_t*)(ws + 33554432 + 16777216 + 1048576 + 67108864);

  float* y_out = (float*)d_out;
  float* h_out = y_out + (size_t)B_ * OUT_;
  float* c_out = h_out + (size_t)B_ * H_;

  pack_combined<<<dim3(B_), dim3(256), 0, stream>>>(x, h, combined);
  const float* Wg[4] = {Wi, Wf, Wo, Wc};
  for (int g = 0; g < 4; ++g)
    transpose_pack<<<dim3(H_ / 64, KC / 64), dim3(256), 0, stream>>>(
        Wg[g], Wt + (size_t)g * H_ * KC, KC, H_);
  transpose_pack<<<dim3(OUT_ / 64, H_ / 64), dim3(256), 0, stream>>>(
      Wy, Wyt, H_, OUT_);

  // gates = combined @ W_all  (256^2 8-phase template)
  gemm1_8ph<<<dim3((B_ / 256) * (N4 / 256)), dim3(512), 0, stream>>>(
      combined, Wt, gates);

  lstm_eltwise<<<dim3(B_ * H_ / 8 / 256), dim3(256), 0, stream>>>(
      gates, c, bi, bfg, bo, bc, h_out, c_out, hb);

  gemm_bt_f32<<<dim3(OUT_ / 128, B_ / 128), dim3(256), 0, stream>>>(
      hb, Wyt, y_out, by, B_, OUT_, H_);
}

// Round 3
// 212.178 us; speedup vs baseline: 1.3689x; 1.0690x over previous
//
#include <hip/hip_runtime.h>
#include <hip/hip_bf16.h>
#include <stdint.h>

#define B_ 8192
#define IN_ 1024
#define H_ 1024
#define OUT_ 512
#define KC 2048   // IN_+H_
#define N4 4096   // 4*H_

typedef __bf16 bf16_t;
typedef __bf16 bf16x8 __attribute__((ext_vector_type(8)));
typedef float f32x4 __attribute__((ext_vector_type(4)));

__device__ __forceinline__ void gload_lds16(const void* g, void* l) {
  __builtin_amdgcn_global_load_lds(
      (const __attribute__((address_space(1))) uint32_t*)g,
      (__attribute__((address_space(3))) uint32_t*)l, 16, 0, 0);
}

__device__ __forceinline__ float fsigmoid(float x) {
  return __builtin_amdgcn_rcpf(1.0f + __expf(-x));
}
__device__ __forceinline__ float ftanh(float x) {
  return 2.0f * __builtin_amdgcn_rcpf(1.0f + __expf(-2.0f * x)) - 1.0f;
}

// ---------------- pack kernels ----------------

__global__ __launch_bounds__(256) void pack_combined(
    const float* __restrict__ x, const float* __restrict__ h,
    bf16_t* __restrict__ out) {
  const int row = blockIdx.x;
  const int j = threadIdx.x * 8;
  const float* src = (j < IN_) ? (x + (size_t)row * IN_ + j)
                               : (h + (size_t)row * H_ + (j - IN_));
  float4 a = ((const float4*)src)[0];
  float4 b = ((const float4*)src)[1];
  bf16x8 v;
  v[0] = (bf16_t)a.x; v[1] = (bf16_t)a.y; v[2] = (bf16_t)a.z; v[3] = (bf16_t)a.w;
  v[4] = (bf16_t)b.x; v[5] = (bf16_t)b.y; v[6] = (bf16_t)b.z; v[7] = (bf16_t)b.w;
  *(bf16x8*)(out + (size_t)row * KC + j) = v;
}

// dst[(n*RS+RO)][k] = src[k][n] as bf16. src is [K][N] f32, dst row stride K.
// RS/RO: row-interleave so gate g's col hcol lands at row hcol*4+g.
__global__ __launch_bounds__(256) void transpose_pack(
    const float* __restrict__ src, bf16_t* __restrict__ dst, int K, int N,
    int RS, int RO) {
  __shared__ float tile[64][65];
  const int k0 = blockIdx.y * 64, n0 = blockIdx.x * 64;
  const int t = threadIdx.x;
  const int tr = t >> 4, tc4 = (t & 15) * 4;
#pragma unroll
  for (int r = 0; r < 4; ++r) {
    const int k = tr + r * 16;
    float4 v = *(const float4*)(src + (size_t)(k0 + k) * N + n0 + tc4);
    tile[k][tc4] = v.x; tile[k][tc4 + 1] = v.y;
    tile[k][tc4 + 2] = v.z; tile[k][tc4 + 3] = v.w;
  }
  __syncthreads();
  const int nr = t >> 3, kc8 = (t & 7) * 8;
#pragma unroll
  for (int r = 0; r < 2; ++r) {
    const int n = nr + r * 32;
    bf16x8 v;
#pragma unroll
    for (int q = 0; q < 8; ++q) v[q] = (bf16_t)tile[kc8 + q][n];
    *(bf16x8*)(dst + (size_t)((n0 + n) * RS + RO) * K + k0 + kc8) = v;
  }
}

// ---------------- GEMM1: 256x256 8-phase + fused LSTM epilogue -------------
// gates = A[M][K] * Wt[N][K]^T with Wt rows n' = hcol*4 + g (gate-interleaved)
// then per-element: i,f,o,c~ -> h_new, c_new written directly.
__global__ __launch_bounds__(512) void gemm1_8ph(
    const bf16_t* __restrict__ A, const bf16_t* __restrict__ Bt,
    const float* __restrict__ c_in,
    const float* __restrict__ bi, const float* __restrict__ bfg,
    const float* __restrict__ bo, const float* __restrict__ bc,
    float* __restrict__ h_out, float* __restrict__ c_out,
    bf16_t* __restrict__ hb) {
  constexpr int K = KC;
  constexpr int NT = K / 64;  // 32 K-tiles
  __shared__ char lds[131072];

  const int tid = threadIdx.x;
  const int lane = tid & 63;
  const int w = tid >> 6;
  const int wr = w >> 2, wc = w & 3;
  const int l15 = lane & 15, l4 = lane >> 4;

  // XCD-bijective swizzle: 512 blocks, 8 XCDs, 64 blocks/XCD.
  const int wg = blockIdx.x;
  const int swz = (wg & 7) * 64 + (wg >> 3);
  const int bx = swz >> 5;   // 0..15
  const int by = swz & 31;   // 0..31
  const int m0 = by * 256, n0 = bx * 256;

  // ---- staging: per-lane pre-swizzled global source ----
  const int jrow = lane >> 2;
  const int jcol = ((lane & 3) * 16) ^ ((lane >> 5) << 5);
  const char* Asrc = (const char*)A + (size_t)(m0 + w * 16 + jrow) * (K * 2) + jcol;
  const char* Bsrc = (const char*)Bt + (size_t)(n0 + w * 16 + jrow) * (K * 2) + jcol;
  char* ldsA = lds;
  char* ldsB = lds + 32768;
  const int wchunk = w * 2048;

#define STG_A(buf, h, tt) do {                                            \
    gload_lds16(Asrc + (size_t)(h) * 128 * (K * 2) + (size_t)(tt) * 128,  \
                ldsA + (buf) * 65536 + (h) * 16384 + wchunk);             \
    gload_lds16(Asrc + (size_t)(h) * 128 * (K * 2) + (size_t)(tt) * 128 + 64, \
                ldsA + (buf) * 65536 + (h) * 16384 + wchunk + 1024);      \
  } while (0)
#define STG_B(buf, h, tt) do {                                            \
    gload_lds16(Bsrc + (size_t)(h) * 128 * (K * 2) + (size_t)(tt) * 128,  \
                ldsB + (buf) * 65536 + (h) * 16384 + wchunk);             \
    gload_lds16(Bsrc + (size_t)(h) * 128 * (K * 2) + (size_t)(tt) * 128 + 64, \
                ldsB + (buf) * 65536 + (h) * 16384 + wchunk + 1024);      \
  } while (0)

  const int rdoff = l15 * 64 + ((l4 * 16) ^ ((l15 >> 3) << 5));
  const char* ldsArd = lds + wr * 16384 + rdoff;
  const char* ldsBrd = lds + 32768 + (wc >> 1) * 16384 + (wc & 1) * 8192 + rdoff;

  f32x4 acc[8][4] = {};
  bf16x8 fa[4][2], fb[4][2];

  // kk-OUTER: 8 independent MFMAs per round; round 2 deps at distance 8.
#define MFMA_Q(MIBASE, NIBASE)                                                \
  do {                                                                        \
    __builtin_amdgcn_s_setprio(1);                                            \
    _Pragma("unroll") for (int kk = 0; kk < 2; ++kk)                          \
        _Pragma("unroll") for (int mi = 0; mi < 4; ++mi)                      \
            _Pragma("unroll") for (int ni = 0; ni < 2; ++ni)                  \
                acc[(MIBASE) + mi][(NIBASE) + ni] =                           \
                    __builtin_amdgcn_mfma_f32_16x16x32_bf16(                  \
                        fa[mi][kk], fb[(NIBASE) + ni][kk],                    \
                        acc[(MIBASE) + mi][(NIBASE) + ni], 0, 0, 0);          \
    __builtin_amdgcn_s_setprio(0);                                            \
  } while (0)

  // ---- prologue ----
  STG_B(0, 0, 0); STG_A(0, 0, 0); STG_A(0, 1, 0); STG_B(0, 1, 0);
  STG_B(1, 0, 1); STG_A(1, 0, 1); STG_A(1, 1, 1);
  asm volatile("s_waitcnt vmcnt(6)" ::: "memory");
  __builtin_amdgcn_s_barrier();

  for (int t = 0; t < NT; ++t) {
    const int buf = t & 1;
    const int nbuf = buf ^ 1;
    const char* ard = ldsArd + buf * 65536;
    const char* brd = ldsBrd + buf * 65536;
    const bool st1 = (t + 1 < NT);
    const bool st2 = (t + 2 < NT);

    // P1: (m-lo, n-lo); 12 ds_reads
#pragma unroll
    for (int mi = 0; mi < 4; ++mi)
#pragma unroll
      for (int kk = 0; kk < 2; ++kk)
        fa[mi][kk] = *(const bf16x8*)(ard + mi * 2048 + kk * 1024);
#pragma unroll
    for (int ni = 0; ni < 2; ++ni)
#pragma unroll
      for (int kk = 0; kk < 2; ++kk)
        fb[ni][kk] = *(const bf16x8*)(brd + ni * 2048 + kk * 1024);
    if (st1) STG_B(nbuf, 1, t + 1);
    __builtin_amdgcn_s_barrier();
    MFMA_Q(0, 0);
    __builtin_amdgcn_s_barrier();

    // P2: (m-lo, n-hi); 4 ds_reads
#pragma unroll
    for (int ni = 2; ni < 4; ++ni)
#pragma unroll
      for (int kk = 0; kk < 2; ++kk)
        fb[ni][kk] = *(const bf16x8*)(brd + ni * 2048 + kk * 1024);
    __builtin_amdgcn_s_barrier();
    MFMA_Q(0, 2);
    __builtin_amdgcn_s_barrier();

    // P3: (m-hi, n-lo); 8 ds_reads
#pragma unroll
    for (int mi = 0; mi < 4; ++mi)
#pragma unroll
      for (int kk = 0; kk < 2; ++kk)
        fa[mi][kk] = *(const bf16x8*)(ard + (mi + 4) * 2048 + kk * 1024);
    if (st2) STG_B(buf, 0, t + 2);
    __builtin_amdgcn_s_barrier();
    MFMA_Q(4, 0);
    __builtin_amdgcn_s_barrier();

    // P4: (m-hi, n-hi); 0 ds_reads
    if (st2) { STG_A(buf, 0, t + 2); STG_A(buf, 1, t + 2); }
    __builtin_amdgcn_s_barrier();
    MFMA_Q(4, 2);
    if (st2) asm volatile("s_waitcnt vmcnt(6)" ::: "memory");
    else     asm volatile("s_waitcnt vmcnt(0)" ::: "memory");
    __builtin_amdgcn_s_barrier();
  }

  // ---- fused LSTM epilogue ----
  // acc element (mi,ni,q): row = wr*128 + mi*16 + l4*4 + q,
  //                        n'  = wc*64 + ni*16 + l15; hc = n'>>2, g = n'&3.
  // LDS chunk layout (64 rows x 1KB): byte = rr*1024 + ((hc ^ rr)*16) + g*4.
  const int hc0 = n0 >> 2;
  float* ldsF = (float*)lds;
  const int ehc = tid & 63;
  const int err0 = (tid >> 6) * 8;
  const float bI = bi[hc0 + ehc];
  const float bF = bfg[hc0 + ehc];
  const float bO = bo[hc0 + ehc];
  const float bC = bc[hc0 + ehc];

  for (int ch = 0; ch < 4; ++ch) {
    __builtin_amdgcn_s_barrier();
    if (wr == (ch >> 1)) {
      const int mib = (ch & 1) * 4;
#pragma unroll
      for (int mi = 0; mi < 4; ++mi)
#pragma unroll
        for (int ni = 0; ni < 4; ++ni) {
          const int col = wc * 64 + ni * 16 + l15;
          const int hc = col >> 2, g = col & 3;
#pragma unroll
          for (int q = 0; q < 4; ++q) {
            const int rr = mi * 16 + l4 * 4 + q;
            ldsF[rr * 256 + ((hc ^ rr) * 4) + g] = acc[mib + mi][ni][q];
          }
        }
    }
    __builtin_amdgcn_s_barrier();
#pragma unroll
    for (int r = 0; r < 8; ++r) {
      const int rr = err0 + r;
      f32x4 gq = *(const f32x4*)&ldsF[rr * 256 + ((ehc ^ rr) * 4)];
      const size_t gidx = (size_t)(m0 + ch * 64 + rr) * H_ + hc0 + ehc;
      float I = fsigmoid(gq[0] + bI);
      float F = fsigmoid(gq[1] + bF);
      float O = fsigmoid(gq[2] + bO);
      float Ct = ftanh(gq[3] + bC);
      float cn = F * c_in[gidx] + I * Ct;
      float hn = O * ftanh(cn);
      c_out[gidx] = cn;
      h_out[gidx] = hn;
      hb[gidx] = (bf16_t)hn;
    }
  }
#undef STG_A
#undef STG_B
#undef MFMA_Q
}

// ---------------- GEMM2 (m97 structure, f32 out + bias) ----------------
__global__ __launch_bounds__(256) void gemm_bt_f32(
    const bf16_t* __restrict__ A, const bf16_t* __restrict__ Bt,
    float* __restrict__ Cout, const float* __restrict__ bias,
    int M, int N, int K) {
  __shared__ bf16_t As[128 * 64];
  __shared__ bf16_t Bs[128 * 64];
  const int tid = threadIdx.x;
  const int lane = tid & 63;
  const int wave = tid >> 6;
  const int m0 = blockIdx.y * 128;
  const int n0 = blockIdx.x * 128;
  const int wr = wave >> 1, wc = wave & 1;
  const int l15 = lane & 15, l4 = lane >> 4;

  f32x4 acc[4][4] = {};

  const int srow = tid >> 3;
  const int skel = (tid & 7) * 8;
  const size_t aBase = (size_t)(m0 + srow) * K + skel;
  const size_t bBase = (size_t)(n0 + srow) * K + skel;
  char* aL = (char*)As + wave * 1024;
  char* bL = (char*)Bs + wave * 1024;

  for (int kt = 0; kt < K; kt += 64) {
    __syncthreads();
#pragma unroll
    for (int i = 0; i < 4; ++i) {
      gload_lds16(A + aBase + (size_t)i * 32 * K + kt, aL + i * 4096);
      gload_lds16(Bt + bBase + (size_t)i * 32 * K + kt, bL + i * 4096);
    }
    __syncthreads();
#pragma unroll
    for (int kk = 0; kk < 2; ++kk) {
      bf16x8 af[4], bq[4];
#pragma unroll
      for (int mi = 0; mi < 4; ++mi)
        af[mi] = *(const bf16x8*)((const char*)As +
                 (wr * 64 + mi * 16 + l15) * 128 + kk * 64 + l4 * 16);
#pragma unroll
      for (int ni = 0; ni < 4; ++ni)
        bq[ni] = *(const bf16x8*)((const char*)Bs +
                 (wc * 64 + ni * 16 + l15) * 128 + kk * 64 + l4 * 16);
#pragma unroll
      for (int mi = 0; mi < 4; ++mi)
#pragma unroll
        for (int ni = 0; ni < 4; ++ni)
          acc[mi][ni] = __builtin_amdgcn_mfma_f32_16x16x32_bf16(
              af[mi], bq[ni], acc[mi][ni], 0, 0, 0);
    }
  }

  const int col = n0 + wc * 64 + l15;
  const int row0 = m0 + wr * 64 + l4 * 4;
#pragma unroll
  for (int ni = 0; ni < 4; ++ni) {
    const float bv = bias[col + ni * 16];
#pragma unroll
    for (int mi = 0; mi < 4; ++mi)
#pragma unroll
      for (int q = 0; q < 4; ++q)
        Cout[(size_t)(row0 + mi * 16 + q) * N + col + ni * 16] =
            acc[mi][ni][q] + bv;
  }
}

// ---------------- launcher ----------------
extern "C" void kernel_launch(void* const* d_in, const int* in_sizes, int n_in,
                              void* d_out, int out_size, void* d_ws,
                              size_t ws_size, hipStream_t stream) {
  const float* x = (const float*)d_in[0];
  const float* h = (const float*)d_in[1];
  const float* c = (const float*)d_in[2];
  const float* Wi = (const float*)d_in[3];
  const float* bi = (const float*)d_in[4];
  const float* Wf = (const float*)d_in[5];
  const float* bfg = (const float*)d_in[6];
  const float* Wo = (const float*)d_in[7];
  const float* bo = (const float*)d_in[8];
  const float* Wc = (const float*)d_in[9];
  const float* bc = (const float*)d_in[10];
  const float* Wy = (const float*)d_in[11];
  const float* by = (const float*)d_in[12];

  char* ws = (char*)d_ws;
  bf16_t* combined = (bf16_t*)ws;                       // 33.5 MB
  bf16_t* Wt = (bf16_t*)(ws + 33554432);                // 16.8 MB (interleaved)
  bf16_t* Wyt = (bf16_t*)(ws + 33554432 + 16777216);    // 1 MB
  bf16_t* hb = (bf16_t*)(ws + 33554432 + 16777216 + 1048576);  // 16.8 MB

  float* y_out = (float*)d_out;
  float* h_out = y_out + (size_t)B_ * OUT_;
  float* c_out = h_out + (size_t)B_ * H_;

  pack_combined<<<dim3(B_), dim3(256), 0, stream>>>(x, h, combined);
  const float* Wg[4] = {Wi, Wf, Wo, Wc};
  for (int g = 0; g < 4; ++g)
    transpose_pack<<<dim3(H_ / 64, KC / 64), dim3(256), 0, stream>>>(
        Wg[g], Wt, KC, H_, 4, g);   // row n' = hcol*4 + g
  transpose_pack<<<dim3(OUT_ / 64, H_ / 64), dim3(256), 0, stream>>>(
      Wy, Wyt, H_, OUT_, 1, 0);

  gemm1_8ph<<<dim3((B_ / 256) * (N4 / 256)), dim3(512), 0, stream>>>(
      combined, Wt, c, bi, bfg, bo, bc, h_out, c_out, hb);

  gemm_bt_f32<<<dim3(OUT_ / 128, B_ / 128), dim3(256), 0, stream>>>(
      hb, Wyt, y_out, by, B_, OUT_, H_);
}

// Round 4
// 197.529 us; speedup vs baseline: 1.4704x; 1.0742x over previous
//
#include <hip/hip_runtime.h>
#include <hip/hip_bf16.h>
#include <stdint.h>

#define B_ 8192
#define IN_ 1024
#define H_ 1024
#define OUT_ 512
#define KC 2048   // IN_+H_
#define N4 4096   // 4*H_

typedef __bf16 bf16_t;
typedef __bf16 bf16x8 __attribute__((ext_vector_type(8)));
typedef float f32x4 __attribute__((ext_vector_type(4)));

__device__ __forceinline__ void gload_lds16(const void* g, void* l) {
  __builtin_amdgcn_global_load_lds(
      (const __attribute__((address_space(1))) uint32_t*)g,
      (__attribute__((address_space(3))) uint32_t*)l, 16, 0, 0);
}

__device__ __forceinline__ float fsigmoid(float x) {
  return __builtin_amdgcn_rcpf(1.0f + __expf(-x));
}
__device__ __forceinline__ float ftanh(float x) {
  return 2.0f * __builtin_amdgcn_rcpf(1.0f + __expf(-2.0f * x)) - 1.0f;
}

// ---------------- pack kernels ----------------

__global__ __launch_bounds__(256) void pack_combined(
    const float* __restrict__ x, const float* __restrict__ h,
    bf16_t* __restrict__ out) {
  const int row = blockIdx.x;
  const int j = threadIdx.x * 8;
  const float* src = (j < IN_) ? (x + (size_t)row * IN_ + j)
                               : (h + (size_t)row * H_ + (j - IN_));
  float4 a = ((const float4*)src)[0];
  float4 b = ((const float4*)src)[1];
  bf16x8 v;
  v[0] = (bf16_t)a.x; v[1] = (bf16_t)a.y; v[2] = (bf16_t)a.z; v[3] = (bf16_t)a.w;
  v[4] = (bf16_t)b.x; v[5] = (bf16_t)b.y; v[6] = (bf16_t)b.z; v[7] = (bf16_t)b.w;
  *(bf16x8*)(out + (size_t)row * KC + j) = v;
}

// Transpose all 4 gate weights in one launch: dst[(n*4+g)][k] = Wg[k][n].
// grid: (H_/64, KC/64, 4), block 256.
__global__ __launch_bounds__(256) void transpose_pack4(
    const float* __restrict__ Wi, const float* __restrict__ Wf,
    const float* __restrict__ Wo, const float* __restrict__ Wc,
    bf16_t* __restrict__ dst) {
  const int g = blockIdx.z;
  const float* src = (g == 0) ? Wi : (g == 1) ? Wf : (g == 2) ? Wo : Wc;
  __shared__ float tile[64][65];
  const int k0 = blockIdx.y * 64, n0 = blockIdx.x * 64;
  const int t = threadIdx.x;
  const int tr = t >> 4, tc4 = (t & 15) * 4;
#pragma unroll
  for (int r = 0; r < 4; ++r) {
    const int k = tr + r * 16;
    float4 v = *(const float4*)(src + (size_t)(k0 + k) * H_ + n0 + tc4);
    tile[k][tc4] = v.x; tile[k][tc4 + 1] = v.y;
    tile[k][tc4 + 2] = v.z; tile[k][tc4 + 3] = v.w;
  }
  __syncthreads();
  const int nr = t >> 3, kc8 = (t & 7) * 8;
#pragma unroll
  for (int r = 0; r < 2; ++r) {
    const int n = nr + r * 32;
    bf16x8 v;
#pragma unroll
    for (int q = 0; q < 8; ++q) v[q] = (bf16_t)tile[kc8 + q][n];
    *(bf16x8*)(dst + (size_t)((n0 + n) * 4 + g) * KC + k0 + kc8) = v;
  }
}

// Generic single-matrix transpose-pack (for Wy). dst[n][k] = src[k][n].
__global__ __launch_bounds__(256) void transpose_pack(
    const float* __restrict__ src, bf16_t* __restrict__ dst, int K, int N) {
  __shared__ float tile[64][65];
  const int k0 = blockIdx.y * 64, n0 = blockIdx.x * 64;
  const int t = threadIdx.x;
  const int tr = t >> 4, tc4 = (t & 15) * 4;
#pragma unroll
  for (int r = 0; r < 4; ++r) {
    const int k = tr + r * 16;
    float4 v = *(const float4*)(src + (size_t)(k0 + k) * N + n0 + tc4);
    tile[k][tc4] = v.x; tile[k][tc4 + 1] = v.y;
    tile[k][tc4 + 2] = v.z; tile[k][tc4 + 3] = v.w;
  }
  __syncthreads();
  const int nr = t >> 3, kc8 = (t & 7) * 8;
#pragma unroll
  for (int r = 0; r < 2; ++r) {
    const int n = nr + r * 32;
    bf16x8 v;
#pragma unroll
    for (int q = 0; q < 8; ++q) v[q] = (bf16_t)tile[kc8 + q][n];
    *(bf16x8*)(dst + (size_t)(n0 + n) * K + k0 + kc8) = v;
  }
}

// ---------------- GEMM1: 256x256, 1 barrier/K-tile, fused LSTM epilogue ----
// gates = A[M][K] * Wt[N][K]^T with Wt rows n' = hcol*4 + g (gate-interleaved)
// All staging targets the OTHER buffer -> no intra-tile LDS hazards -> waves
// free-run within a tile; per-wave counted lgkmcnt pipelines reads vs MFMA.
__global__ __launch_bounds__(512) void gemm1_8ph(
    const bf16_t* __restrict__ A, const bf16_t* __restrict__ Bt,
    const float* __restrict__ c_in,
    const float* __restrict__ bi, const float* __restrict__ bfg,
    const float* __restrict__ bo, const float* __restrict__ bc,
    float* __restrict__ h_out, float* __restrict__ c_out,
    bf16_t* __restrict__ hb) {
  constexpr int K = KC;
  constexpr int NT = K / 64;  // 32 K-tiles
  __shared__ char lds[131072];

  const int tid = threadIdx.x;
  const int lane = tid & 63;
  const int w = tid >> 6;
  const int wr = w >> 2, wc = w & 3;
  const int l15 = lane & 15, l4 = lane >> 4;

  // XCD-bijective swizzle: 512 blocks, 8 XCDs, 64 blocks/XCD.
  const int wg = blockIdx.x;
  const int swz = (wg & 7) * 64 + (wg >> 3);
  const int bx = swz >> 5;   // 0..15
  const int by = swz & 31;   // 0..31
  const int m0 = by * 256, n0 = bx * 256;

  // ---- staging: per-lane pre-swizzled global source ----
  const int jrow = lane >> 2;
  const int jcol = ((lane & 3) * 16) ^ ((lane >> 5) << 5);
  const char* Asrc = (const char*)A + (size_t)(m0 + w * 16 + jrow) * (K * 2) + jcol;
  const char* Bsrc = (const char*)Bt + (size_t)(n0 + w * 16 + jrow) * (K * 2) + jcol;
  char* ldsA = lds;
  char* ldsB = lds + 32768;
  const int wchunk = w * 2048;

#define STG_A(buf, h, tt) do {                                            \
    gload_lds16(Asrc + (size_t)(h) * 128 * (K * 2) + (size_t)(tt) * 128,  \
                ldsA + (buf) * 65536 + (h) * 16384 + wchunk);             \
    gload_lds16(Asrc + (size_t)(h) * 128 * (K * 2) + (size_t)(tt) * 128 + 64, \
                ldsA + (buf) * 65536 + (h) * 16384 + wchunk + 1024);      \
  } while (0)
#define STG_B(buf, h, tt) do {                                            \
    gload_lds16(Bsrc + (size_t)(h) * 128 * (K * 2) + (size_t)(tt) * 128,  \
                ldsB + (buf) * 65536 + (h) * 16384 + wchunk);             \
    gload_lds16(Bsrc + (size_t)(h) * 128 * (K * 2) + (size_t)(tt) * 128 + 64, \
                ldsB + (buf) * 65536 + (h) * 16384 + wchunk + 1024);      \
  } while (0)

  const int rdoff = l15 * 64 + ((l4 * 16) ^ ((l15 >> 3) << 5));
  const char* ldsArd = lds + wr * 16384 + rdoff;
  const char* ldsBrd = lds + 32768 + (wc >> 1) * 16384 + (wc & 1) * 8192 + rdoff;

  f32x4 acc[8][4] = {};
  bf16x8 falo[4][2], fahi[4][2], fb[4][2];

  // ---- prologue: tile 0 into buf 0 ----
  STG_B(0, 0, 0); STG_B(0, 1, 0); STG_A(0, 0, 0); STG_A(0, 1, 0);
  asm volatile("s_waitcnt vmcnt(0)" ::: "memory");
  __builtin_amdgcn_s_barrier();

  for (int t = 0; t < NT; ++t) {
    const int buf = t & 1;
    const int nbuf = buf ^ 1;
    const char* ard = ldsArd + buf * 65536;
    const char* brd = ldsBrd + buf * 65536;
    const bool st1 = (t + 1 < NT);

    // issue lo A-fragments + all B-fragments (16 ds_read_b128)
#pragma unroll
    for (int mi = 0; mi < 4; ++mi)
#pragma unroll
      for (int kk = 0; kk < 2; ++kk)
        falo[mi][kk] = *(const bf16x8*)(ard + mi * 2048 + kk * 1024);
#pragma unroll
    for (int ni = 0; ni < 4; ++ni)
#pragma unroll
      for (int kk = 0; kk < 2; ++kk)
        fb[ni][kk] = *(const bf16x8*)(brd + ni * 2048 + kk * 1024);

    // stage ALL of tile t+1 into the other buffer (8 gloads, lands by tile end)
    if (st1) {
      STG_B(nbuf, 0, t + 1); STG_B(nbuf, 1, t + 1);
      STG_A(nbuf, 0, t + 1); STG_A(nbuf, 1, t + 1);
    }

    // issue hi A-fragments (8 ds_read_b128)
#pragma unroll
    for (int mi = 0; mi < 4; ++mi)
#pragma unroll
      for (int kk = 0; kk < 2; ++kk)
        fahi[mi][kk] = *(const bf16x8*)(ard + (mi + 4) * 2048 + kk * 1024);

    // MFMA cluster 1: m-lo x all n (32)
    __builtin_amdgcn_s_setprio(1);
#pragma unroll
    for (int kk = 0; kk < 2; ++kk)
#pragma unroll
      for (int mi = 0; mi < 4; ++mi)
#pragma unroll
        for (int ni = 0; ni < 4; ++ni)
          acc[mi][ni] = __builtin_amdgcn_mfma_f32_16x16x32_bf16(
              falo[mi][kk], fb[ni][kk], acc[mi][ni], 0, 0, 0);
    __builtin_amdgcn_s_setprio(0);

    // MFMA cluster 2: m-hi x all n (32)
    __builtin_amdgcn_s_setprio(1);
#pragma unroll
    for (int kk = 0; kk < 2; ++kk)
#pragma unroll
      for (int mi = 0; mi < 4; ++mi)
#pragma unroll
        for (int ni = 0; ni < 4; ++ni)
          acc[mi + 4][ni] = __builtin_amdgcn_mfma_f32_16x16x32_bf16(
              fahi[mi][kk], fb[ni][kk], acc[mi + 4][ni], 0, 0, 0);
    __builtin_amdgcn_s_setprio(0);

    if (st1) asm volatile("s_waitcnt vmcnt(0)" ::: "memory");
    __builtin_amdgcn_s_barrier();  // tile t+1 resident; buf roles swap
  }

  // ---- fused LSTM epilogue ----
  // acc element (mi,ni,q): row = wr*128 + mi*16 + l4*4 + q,
  //                        n'  = wc*64 + ni*16 + l15; hc = n'>>2, g = n'&3.
  // LDS chunk layout (64 rows x 1KB): byte = rr*1024 + ((hc ^ rr)*16) + g*4.
  const int hc0 = n0 >> 2;
  float* ldsF = (float*)lds;
  const int ehc = tid & 63;
  const int err0 = (tid >> 6) * 8;
  const float bI = bi[hc0 + ehc];
  const float bF = bfg[hc0 + ehc];
  const float bO = bo[hc0 + ehc];
  const float bC = bc[hc0 + ehc];

  for (int ch = 0; ch < 4; ++ch) {
    __builtin_amdgcn_s_barrier();
    if (wr == (ch >> 1)) {
      const int mib = (ch & 1) * 4;
#pragma unroll
      for (int mi = 0; mi < 4; ++mi)
#pragma unroll
        for (int ni = 0; ni < 4; ++ni) {
          const int col = wc * 64 + ni * 16 + l15;
          const int hc = col >> 2, g = col & 3;
#pragma unroll
          for (int q = 0; q < 4; ++q) {
            const int rr = mi * 16 + l4 * 4 + q;
            ldsF[rr * 256 + ((hc ^ rr) * 4) + g] = acc[mib + mi][ni][q];
          }
        }
    }
    __builtin_amdgcn_s_barrier();
#pragma unroll
    for (int r = 0; r < 8; ++r) {
      const int rr = err0 + r;
      f32x4 gq = *(const f32x4*)&ldsF[rr * 256 + ((ehc ^ rr) * 4)];
      const size_t gidx = (size_t)(m0 + ch * 64 + rr) * H_ + hc0 + ehc;
      float I = fsigmoid(gq[0] + bI);
      float F = fsigmoid(gq[1] + bF);
      float O = fsigmoid(gq[2] + bO);
      float Ct = ftanh(gq[3] + bC);
      float cn = F * c_in[gidx] + I * Ct;
      float hn = O * ftanh(cn);
      c_out[gidx] = cn;
      h_out[gidx] = hn;
      hb[gidx] = (bf16_t)hn;
    }
  }
#undef STG_A
#undef STG_B
}

// ---------------- GEMM2 (m97 structure, f32 out + bias) ----------------
__global__ __launch_bounds__(256) void gemm_bt_f32(
    const bf16_t* __restrict__ A, const bf16_t* __restrict__ Bt,
    float* __restrict__ Cout, const float* __restrict__ bias,
    int M, int N, int K) {
  __shared__ bf16_t As[128 * 64];
  __shared__ bf16_t Bs[128 * 64];
  const int tid = threadIdx.x;
  const int lane = tid & 63;
  const int wave = tid >> 6;
  const int m0 = blockIdx.y * 128;
  const int n0 = blockIdx.x * 128;
  const int wr = wave >> 1, wc = wave & 1;
  const int l15 = lane & 15, l4 = lane >> 4;

  f32x4 acc[4][4] = {};

  const int srow = tid >> 3;
  const int skel = (tid & 7) * 8;
  const size_t aBase = (size_t)(m0 + srow) * K + skel;
  const size_t bBase = (size_t)(n0 + srow) * K + skel;
  char* aL = (char*)As + wave * 1024;
  char* bL = (char*)Bs + wave * 1024;

  for (int kt = 0; kt < K; kt += 64) {
    __syncthreads();
#pragma unroll
    for (int i = 0; i < 4; ++i) {
      gload_lds16(A + aBase + (size_t)i * 32 * K + kt, aL + i * 4096);
      gload_lds16(Bt + bBase + (size_t)i * 32 * K + kt, bL + i * 4096);
    }
    __syncthreads();
#pragma unroll
    for (int kk = 0; kk < 2; ++kk) {
      bf16x8 af[4], bq[4];
#pragma unroll
      for (int mi = 0; mi < 4; ++mi)
        af[mi] = *(const bf16x8*)((const char*)As +
                 (wr * 64 + mi * 16 + l15) * 128 + kk * 64 + l4 * 16);
#pragma unroll
      for (int ni = 0; ni < 4; ++ni)
        bq[ni] = *(const bf16x8*)((const char*)Bs +
                 (wc * 64 + ni * 16 + l15) * 128 + kk * 64 + l4 * 16);
#pragma unroll
      for (int mi = 0; mi < 4; ++mi)
#pragma unroll
        for (int ni = 0; ni < 4; ++ni)
          acc[mi][ni] = __builtin_amdgcn_mfma_f32_16x16x32_bf16(
              af[mi], bq[ni], acc[mi][ni], 0, 0, 0);
    }
  }

  const int col = n0 + wc * 64 + l15;
  const int row0 = m0 + wr * 64 + l4 * 4;
#pragma unroll
  for (int ni = 0; ni < 4; ++ni) {
    const float bv = bias[col + ni * 16];
#pragma unroll
    for (int mi = 0; mi < 4; ++mi)
#pragma unroll
      for (int q = 0; q < 4; ++q)
        Cout[(size_t)(row0 + mi * 16 + q) * N + col + ni * 16] =
            acc[mi][ni][q] + bv;
  }
}

// ---------------- launcher ----------------
extern "C" void kernel_launch(void* const* d_in, const int* in_sizes, int n_in,
                              void* d_out, int out_size, void* d_ws,
                              size_t ws_size, hipStream_t stream) {
  const float* x = (const float*)d_in[0];
  const float* h = (const float*)d_in[1];
  const float* c = (const float*)d_in[2];
  const float* Wi = (const float*)d_in[3];
  const float* bi = (const float*)d_in[4];
  const float* Wf = (const float*)d_in[5];
  const float* bfg = (const float*)d_in[6];
  const float* Wo = (const float*)d_in[7];
  const float* bo = (const float*)d_in[8];
  const float* Wc = (const float*)d_in[9];
  const float* bc = (const float*)d_in[10];
  const float* Wy = (const float*)d_in[11];
  const float* by = (const float*)d_in[12];

  char* ws = (char*)d_ws;
  bf16_t* combined = (bf16_t*)ws;                       // 33.5 MB
  bf16_t* Wt = (bf16_t*)(ws + 33554432);                // 16.8 MB (interleaved)
  bf16_t* Wyt = (bf16_t*)(ws + 33554432 + 16777216);    // 1 MB
  bf16_t* hb = (bf16_t*)(ws + 33554432 + 16777216 + 1048576);  // 16.8 MB

  float* y_out = (float*)d_out;
  float* h_out = y_out + (size_t)B_ * OUT_;
  float* c_out = h_out + (size_t)B_ * H_;

  pack_combined<<<dim3(B_), dim3(256), 0, stream>>>(x, h, combined);
  transpose_pack4<<<dim3(H_ / 64, KC / 64, 4), dim3(256), 0, stream>>>(
      Wi, Wf, Wo, Wc, Wt);
  transpose_pack<<<dim3(OUT_ / 64, H_ / 64), dim3(256), 0, stream>>>(
      Wy, Wyt, H_, OUT_);

  gemm1_8ph<<<dim3((B_ / 256) * (N4 / 256)), dim3(512), 0, stream>>>(
      combined, Wt, c, bi, bfg, bo, bc, h_out, c_out, hb);

  gemm_bt_f32<<<dim3(OUT_ / 128, B_ / 128), dim3(256), 0, stream>>>(
      hb, Wyt, y_out, by, B_, OUT_, H_);
}

// Round 5
// 196.216 us; speedup vs baseline: 1.4802x; 1.0067x over previous
//
#include <hip/hip_runtime.h>
#include <hip/hip_bf16.h>
#include <stdint.h>

#define B_ 8192
#define IN_ 1024
#define H_ 1024
#define OUT_ 512
#define KC 2048   // IN_+H_
#define N4 4096   // 4*H_

typedef __bf16 bf16_t;
typedef __bf16 bf16x8 __attribute__((ext_vector_type(8)));
typedef float f32x4 __attribute__((ext_vector_type(4)));

__device__ __forceinline__ void gload_lds16(const void* g, void* l) {
  __builtin_amdgcn_global_load_lds(
      (const __attribute__((address_space(1))) uint32_t*)g,
      (__attribute__((address_space(3))) uint32_t*)l, 16, 0, 0);
}

__device__ __forceinline__ float fsigmoid(float x) {
  return __builtin_amdgcn_rcpf(1.0f + __expf(-x));
}
__device__ __forceinline__ float ftanh(float x) {
  return 2.0f * __builtin_amdgcn_rcpf(1.0f + __expf(-2.0f * x)) - 1.0f;
}

// ---------------- pack kernels ----------------

__global__ __launch_bounds__(256) void pack_combined(
    const float* __restrict__ x, const float* __restrict__ h,
    bf16_t* __restrict__ out) {
  const int row = blockIdx.x;
  const int j = threadIdx.x * 8;
  const float* src = (j < IN_) ? (x + (size_t)row * IN_ + j)
                               : (h + (size_t)row * H_ + (j - IN_));
  float4 a = ((const float4*)src)[0];
  float4 b = ((const float4*)src)[1];
  bf16x8 v;
  v[0] = (bf16_t)a.x; v[1] = (bf16_t)a.y; v[2] = (bf16_t)a.z; v[3] = (bf16_t)a.w;
  v[4] = (bf16_t)b.x; v[5] = (bf16_t)b.y; v[6] = (bf16_t)b.z; v[7] = (bf16_t)b.w;
  *(bf16x8*)(out + (size_t)row * KC + j) = v;
}

// Transpose all 4 gate weights in one launch: dst[(n*4+g)][k] = Wg[k][n].
__global__ __launch_bounds__(256) void transpose_pack4(
    const float* __restrict__ Wi, const float* __restrict__ Wf,
    const float* __restrict__ Wo, const float* __restrict__ Wc,
    bf16_t* __restrict__ dst) {
  const int g = blockIdx.z;
  const float* src = (g == 0) ? Wi : (g == 1) ? Wf : (g == 2) ? Wo : Wc;
  __shared__ float tile[64][65];
  const int k0 = blockIdx.y * 64, n0 = blockIdx.x * 64;
  const int t = threadIdx.x;
  const int tr = t >> 4, tc4 = (t & 15) * 4;
#pragma unroll
  for (int r = 0; r < 4; ++r) {
    const int k = tr + r * 16;
    float4 v = *(const float4*)(src + (size_t)(k0 + k) * H_ + n0 + tc4);
    tile[k][tc4] = v.x; tile[k][tc4 + 1] = v.y;
    tile[k][tc4 + 2] = v.z; tile[k][tc4 + 3] = v.w;
  }
  __syncthreads();
  const int nr = t >> 3, kc8 = (t & 7) * 8;
#pragma unroll
  for (int r = 0; r < 2; ++r) {
    const int n = nr + r * 32;
    bf16x8 v;
#pragma unroll
    for (int q = 0; q < 8; ++q) v[q] = (bf16_t)tile[kc8 + q][n];
    *(bf16x8*)(dst + (size_t)((n0 + n) * 4 + g) * KC + k0 + kc8) = v;
  }
}

// Generic single-matrix transpose-pack (for Wy). dst[n][k] = src[k][n].
__global__ __launch_bounds__(256) void transpose_pack(
    const float* __restrict__ src, bf16_t* __restrict__ dst, int K, int N) {
  __shared__ float tile[64][65];
  const int k0 = blockIdx.y * 64, n0 = blockIdx.x * 64;
  const int t = threadIdx.x;
  const int tr = t >> 4, tc4 = (t & 15) * 4;
#pragma unroll
  for (int r = 0; r < 4; ++r) {
    const int k = tr + r * 16;
    float4 v = *(const float4*)(src + (size_t)(k0 + k) * N + n0 + tc4);
    tile[k][tc4] = v.x; tile[k][tc4 + 1] = v.y;
    tile[k][tc4 + 2] = v.z; tile[k][tc4 + 3] = v.w;
  }
  __syncthreads();
  const int nr = t >> 3, kc8 = (t & 7) * 8;
#pragma unroll
  for (int r = 0; r < 2; ++r) {
    const int n = nr + r * 32;
    bf16x8 v;
#pragma unroll
    for (int q = 0; q < 8; ++q) v[q] = (bf16_t)tile[kc8 + q][n];
    *(bf16x8*)(dst + (size_t)(n0 + n) * K + k0 + kc8) = v;
  }
}

// ---------------- GEMM1: 256x256, 1 barrier/K-tile, read-ladder interleave --
__global__ __launch_bounds__(512) void gemm1_8ph(
    const bf16_t* __restrict__ A, const bf16_t* __restrict__ Bt,
    const float* __restrict__ c_in,
    const float* __restrict__ bi, const float* __restrict__ bfg,
    const float* __restrict__ bo, const float* __restrict__ bc,
    float* __restrict__ h_out, float* __restrict__ c_out,
    bf16_t* __restrict__ hb) {
  constexpr int K = KC;
  constexpr int NT = K / 64;  // 32 K-tiles
  __shared__ char lds[131072];

  const int tid = threadIdx.x;
  const int lane = tid & 63;
  const int w = tid >> 6;
  const int wr = w >> 2, wc = w & 3;
  const int l15 = lane & 15, l4 = lane >> 4;

  // XCD-bijective swizzle: 512 blocks, 8 XCDs, 64 blocks/XCD.
  const int wg = blockIdx.x;
  const int swz = (wg & 7) * 64 + (wg >> 3);
  const int bx = swz >> 5;   // 0..15
  const int by = swz & 31;   // 0..31
  const int m0 = by * 256, n0 = bx * 256;

  // ---- staging: per-lane pre-swizzled global source ----
  const int jrow = lane >> 2;
  const int jcol = ((lane & 3) * 16) ^ ((lane >> 5) << 5);
  const char* Asrc = (const char*)A + (size_t)(m0 + w * 16 + jrow) * (K * 2) + jcol;
  const char* Bsrc = (const char*)Bt + (size_t)(n0 + w * 16 + jrow) * (K * 2) + jcol;
  char* ldsA = lds;
  char* ldsB = lds + 32768;
  const int wchunk = w * 2048;

#define STG_A(buf, h, tt) do {                                            \
    gload_lds16(Asrc + (size_t)(h) * 128 * (K * 2) + (size_t)(tt) * 128,  \
                ldsA + (buf) * 65536 + (h) * 16384 + wchunk);             \
    gload_lds16(Asrc + (size_t)(h) * 128 * (K * 2) + (size_t)(tt) * 128 + 64, \
                ldsA + (buf) * 65536 + (h) * 16384 + wchunk + 1024);      \
  } while (0)
#define STG_B(buf, h, tt) do {                                            \
    gload_lds16(Bsrc + (size_t)(h) * 128 * (K * 2) + (size_t)(tt) * 128,  \
                ldsB + (buf) * 65536 + (h) * 16384 + wchunk);             \
    gload_lds16(Bsrc + (size_t)(h) * 128 * (K * 2) + (size_t)(tt) * 128 + 64, \
                ldsB + (buf) * 65536 + (h) * 16384 + wchunk + 1024);      \
  } while (0)

  const int rdoff = l15 * 64 + ((l4 * 16) ^ ((l15 >> 3) << 5));
  const char* ldsArd = lds + wr * 16384 + rdoff;
  const char* ldsBrd = lds + 32768 + (wc >> 1) * 16384 + (wc & 1) * 8192 + rdoff;

  f32x4 acc[8][4] = {};
  bf16x8 falo[4][2], fahi[4][2], fb[4][2];

  // ---- prologue: tile 0 into buf 0 ----
  STG_B(0, 0, 0); STG_B(0, 1, 0); STG_A(0, 0, 0); STG_A(0, 1, 0);
  asm volatile("s_waitcnt vmcnt(0)" ::: "memory");
  __builtin_amdgcn_s_barrier();

  for (int t = 0; t < NT; ++t) {
    const int buf = t & 1;
    const int nbuf = buf ^ 1;
    const char* ard = ldsArd + buf * 65536;
    const char* brd = ldsBrd + buf * 65536;
    const bool st1 = (t + 1 < NT);

    // batch 1 (8 reads): falo[0..1], fb[0..1]
#pragma unroll
    for (int mi = 0; mi < 2; ++mi)
#pragma unroll
      for (int kk = 0; kk < 2; ++kk)
        falo[mi][kk] = *(const bf16x8*)(ard + mi * 2048 + kk * 1024);
#pragma unroll
    for (int ni = 0; ni < 2; ++ni)
#pragma unroll
      for (int kk = 0; kk < 2; ++kk)
        fb[ni][kk] = *(const bf16x8*)(brd + ni * 2048 + kk * 1024);

    // stage tile t+1 into the other buffer (8 gloads)
    if (st1) {
      STG_B(nbuf, 0, t + 1); STG_B(nbuf, 1, t + 1);
      STG_A(nbuf, 0, t + 1); STG_A(nbuf, 1, t + 1);
    }

    // batch 2 (8 reads): falo[2..3], fb[2..3]
#pragma unroll
    for (int mi = 2; mi < 4; ++mi)
#pragma unroll
      for (int kk = 0; kk < 2; ++kk)
        falo[mi][kk] = *(const bf16x8*)(ard + mi * 2048 + kk * 1024);
#pragma unroll
    for (int ni = 2; ni < 4; ++ni)
#pragma unroll
      for (int kk = 0; kk < 2; ++kk)
        fb[ni][kk] = *(const bf16x8*)(brd + ni * 2048 + kk * 1024);

    // batch 3 (8 reads): fahi[0..3]
#pragma unroll
    for (int mi = 0; mi < 4; ++mi)
#pragma unroll
      for (int kk = 0; kk < 2; ++kk)
        fahi[mi][kk] = *(const bf16x8*)(ard + (mi + 4) * 2048 + kk * 1024);

    // C0 (8 MFMA): falo01 x fb01 — needs batch 1 only (lgkm counted)
    __builtin_amdgcn_s_setprio(1);
#pragma unroll
    for (int kk = 0; kk < 2; ++kk)
#pragma unroll
      for (int mi = 0; mi < 2; ++mi)
#pragma unroll
        for (int ni = 0; ni < 2; ++ni)
          acc[mi][ni] = __builtin_amdgcn_mfma_f32_16x16x32_bf16(
              falo[mi][kk], fb[ni][kk], acc[mi][ni], 0, 0, 0);

    // C1 (16 MFMA): falo01 x fb23 + falo23 x fb01 — needs batch 2
#pragma unroll
    for (int kk = 0; kk < 2; ++kk) {
#pragma unroll
      for (int mi = 0; mi < 2; ++mi)
#pragma unroll
        for (int ni = 2; ni < 4; ++ni)
          acc[mi][ni] = __builtin_amdgcn_mfma_f32_16x16x32_bf16(
              falo[mi][kk], fb[ni][kk], acc[mi][ni], 0, 0, 0);
#pragma unroll
      for (int mi = 2; mi < 4; ++mi)
#pragma unroll
        for (int ni = 0; ni < 2; ++ni)
          acc[mi][ni] = __builtin_amdgcn_mfma_f32_16x16x32_bf16(
              falo[mi][kk], fb[ni][kk], acc[mi][ni], 0, 0, 0);
    }

    // C2 (8 MFMA): falo23 x fb23
#pragma unroll
    for (int kk = 0; kk < 2; ++kk)
#pragma unroll
      for (int mi = 2; mi < 4; ++mi)
#pragma unroll
        for (int ni = 2; ni < 4; ++ni)
          acc[mi][ni] = __builtin_amdgcn_mfma_f32_16x16x32_bf16(
              falo[mi][kk], fb[ni][kk], acc[mi][ni], 0, 0, 0);

    // C3 (32 MFMA): fahi x fb (all) — needs batch 3
#pragma unroll
    for (int kk = 0; kk < 2; ++kk)
#pragma unroll
      for (int mi = 0; mi < 4; ++mi)
#pragma unroll
        for (int ni = 0; ni < 4; ++ni)
          acc[mi + 4][ni] = __builtin_amdgcn_mfma_f32_16x16x32_bf16(
              fahi[mi][kk], fb[ni][kk], acc[mi + 4][ni], 0, 0, 0);
    __builtin_amdgcn_s_setprio(0);

    if (st1) asm volatile("s_waitcnt vmcnt(0)" ::: "memory");
    __builtin_amdgcn_s_barrier();  // tile t+1 resident; buf roles swap
  }

  // ---- fused LSTM epilogue (2 passes, both LDS halves) ----
  // acc (mi,ni,q): row = wr*128 + mi*16 + l4*4 + q, col n' = wc*64+ni*16+l15,
  // hc = n'>>2, g = n'&3. Pass p covers chunks (wr,p): rows wr*128+p*64+[0,64).
  // LDS half wr: byte = rr*1024 + ((hc^rr)*16) + g*4.
  const int hc0 = n0 >> 2;
  const int ehc = tid & 63;
  const int err0 = (tid >> 6) * 8;
  const float bI = bi[hc0 + ehc];
  const float bF = bfg[hc0 + ehc];
  const float bO = bo[hc0 + ehc];
  const float bC = bc[hc0 + ehc];

  for (int p = 0; p < 2; ++p) {
    __builtin_amdgcn_s_barrier();
    {
      float* dst = (float*)(lds + wr * 65536);
      const int mib = p * 4;
#pragma unroll
      for (int mi = 0; mi < 4; ++mi)
#pragma unroll
        for (int ni = 0; ni < 4; ++ni) {
          const int col = wc * 64 + ni * 16 + l15;
          const int hc = col >> 2, g = col & 3;
#pragma unroll
          for (int q = 0; q < 4; ++q) {
            const int rr = mi * 16 + l4 * 4 + q;
            dst[rr * 256 + ((hc ^ rr) * 4) + g] = acc[mib + mi][ni][q];
          }
        }
    }
    __builtin_amdgcn_s_barrier();
#pragma unroll
    for (int half = 0; half < 2; ++half) {
      const float* src = (const float*)(lds + half * 65536);
#pragma unroll
      for (int r = 0; r < 8; ++r) {
        const int rr = err0 + r;
        f32x4 gq = *(const f32x4*)&src[rr * 256 + ((ehc ^ rr) * 4)];
        const size_t gidx =
            (size_t)(m0 + half * 128 + p * 64 + rr) * H_ + hc0 + ehc;
        float I = fsigmoid(gq[0] + bI);
        float F = fsigmoid(gq[1] + bF);
        float O = fsigmoid(gq[2] + bO);
        float Ct = ftanh(gq[3] + bC);
        float cn = F * c_in[gidx] + I * Ct;
        float hn = O * ftanh(cn);
        c_out[gidx] = cn;
        h_out[gidx] = hn;
        hb[gidx] = (bf16_t)hn;
      }
    }
  }
#undef STG_A
#undef STG_B
}

// ---------------- GEMM2 (m97 structure, f32 out + bias) ----------------
__global__ __launch_bounds__(256) void gemm_bt_f32(
    const bf16_t* __restrict__ A, const bf16_t* __restrict__ Bt,
    float* __restrict__ Cout, const float* __restrict__ bias,
    int M, int N, int K) {
  __shared__ bf16_t As[128 * 64];
  __shared__ bf16_t Bs[128 * 64];
  const int tid = threadIdx.x;
  const int lane = tid & 63;
  const int wave = tid >> 6;
  const int m0 = blockIdx.y * 128;
  const int n0 = blockIdx.x * 128;
  const int wr = wave >> 1, wc = wave & 1;
  const int l15 = lane & 15, l4 = lane >> 4;

  f32x4 acc[4][4] = {};

  const int srow = tid >> 3;
  const int skel = (tid & 7) * 8;
  const size_t aBase = (size_t)(m0 + srow) * K + skel;
  const size_t bBase = (size_t)(n0 + srow) * K + skel;
  char* aL = (char*)As + wave * 1024;
  char* bL = (char*)Bs + wave * 1024;

  for (int kt = 0; kt < K; kt += 64) {
    __syncthreads();
#pragma unroll
    for (int i = 0; i < 4; ++i) {
      gload_lds16(A + aBase + (size_t)i * 32 * K + kt, aL + i * 4096);
      gload_lds16(Bt + bBase + (size_t)i * 32 * K + kt, bL + i * 4096);
    }
    __syncthreads();
#pragma unroll
    for (int kk = 0; kk < 2; ++kk) {
      bf16x8 af[4], bq[4];
#pragma unroll
      for (int mi = 0; mi < 4; ++mi)
        af[mi] = *(const bf16x8*)((const char*)As +
                 (wr * 64 + mi * 16 + l15) * 128 + kk * 64 + l4 * 16);
#pragma unroll
      for (int ni = 0; ni < 4; ++ni)
        bq[ni] = *(const bf16x8*)((const char*)Bs +
                 (wc * 64 + ni * 16 + l15) * 128 + kk * 64 + l4 * 16);
#pragma unroll
      for (int mi = 0; mi < 4; ++mi)
#pragma unroll
        for (int ni = 0; ni < 4; ++ni)
          acc[mi][ni] = __builtin_amdgcn_mfma_f32_16x16x32_bf16(
              af[mi], bq[ni], acc[mi][ni], 0, 0, 0);
    }
  }

  const int col = n0 + wc * 64 + l15;
  const int row0 = m0 + wr * 64 + l4 * 4;
#pragma unroll
  for (int ni = 0; ni < 4; ++ni) {
    const float bv = bias[col + ni * 16];
#pragma unroll
    for (int mi = 0; mi < 4; ++mi)
#pragma unroll
      for (int q = 0; q < 4; ++q)
        Cout[(size_t)(row0 + mi * 16 + q) * N + col + ni * 16] =
            acc[mi][ni][q] + bv;
  }
}

// ---------------- launcher ----------------
extern "C" void kernel_launch(void* const* d_in, const int* in_sizes, int n_in,
                              void* d_out, int out_size, void* d_ws,
                              size_t ws_size, hipStream_t stream) {
  const float* x = (const float*)d_in[0];
  const float* h = (const float*)d_in[1];
  const float* c = (const float*)d_in[2];
  const float* Wi = (const float*)d_in[3];
  const float* bi = (const float*)d_in[4];
  const float* Wf = (const float*)d_in[5];
  const float* bfg = (const float*)d_in[6];
  const float* Wo = (const float*)d_in[7];
  const float* bo = (const float*)d_in[8];
  const float* Wc = (const float*)d_in[9];
  const float* bc = (const float*)d_in[10];
  const float* Wy = (const float*)d_in[11];
  const float* by = (const float*)d_in[12];

  char* ws = (char*)d_ws;
  bf16_t* combined = (bf16_t*)ws;                       // 33.5 MB
  bf16_t* Wt = (bf16_t*)(ws + 33554432);                // 16.8 MB (interleaved)
  bf16_t* Wyt = (bf16_t*)(ws + 33554432 + 16777216);    // 1 MB
  bf16_t* hb = (bf16_t*)(ws + 33554432 + 16777216 + 1048576);  // 16.8 MB

  float* y_out = (float*)d_out;
  float* h_out = y_out + (size_t)B_ * OUT_;
  float* c_out = h_out + (size_t)B_ * H_;

  pack_combined<<<dim3(B_), dim3(256), 0, stream>>>(x, h, combined);
  transpose_pack4<<<dim3(H_ / 64, KC / 64, 4), dim3(256), 0, stream>>>(
      Wi, Wf, Wo, Wc, Wt);
  transpose_pack<<<dim3(OUT_ / 64, H_ / 64), dim3(256), 0, stream>>>(
      Wy, Wyt, H_, OUT_);

  gemm1_8ph<<<dim3((B_ / 256) * (N4 / 256)), dim3(512), 0, stream>>>(
      combined, Wt, c, bi, bfg, bo, bc, h_out, c_out, hb);

  gemm_bt_f32<<<dim3(OUT_ / 128, B_ / 128), dim3(256), 0, stream>>>(
      hb, Wyt, y_out, by, B_, OUT_, H_);
}